// Round 11
// baseline (136.242 us; speedup 1.0000x reference)
//
#include <hip/hip_runtime.h>
#include <hip/hip_fp16.h>

#define BB 4
#define HH 128
#define WW 128
#define CC 32
#define OH 120
#define OW 120
#define KT 25
#define OFFC 100
#define FF 64
#define NPX 32
#define NTHREADS 512

// window geometry: rows [oy-2, oy+10] (13), cols [ox0-2, ox0+42] (45)
#define WROWS 13
#define WCOLS 45
#define WPIX  (WROWS * WCOLS)        // 585 pixels
#define WUNITS (WPIX * 4)            // 2340 16B-units

typedef __attribute__((ext_vector_type(8))) short    s16x8;
typedef __attribute__((ext_vector_type(8))) _Float16 f16x8;
typedef __attribute__((ext_vector_type(2))) _Float16 h2;
typedef __attribute__((ext_vector_type(4))) float    f32x4;

// d_ws layout (short elements, fp16 bits):
//   WB:  [25 taps][7 n][64 lane][8]   89,600   (offset-conv weights, B-frag)
//   WD:  [4 n][25 taps][64 lane][8]   51,200   (dcn weights, B-frag)
#define WB_ELEMS   (KT * 7 * 64 * 8)
#define WD_ELEMS   (4 * KT * 64 * 8)

__device__ __forceinline__ short f2h(float x) {
    _Float16 h = (_Float16)x;
    return __builtin_bit_cast(short, h);
}
__device__ __forceinline__ float h2f(short x) {
    return (float)__builtin_bit_cast(_Float16, x);
}
__device__ __forceinline__ unsigned pk2(float a, float b) {
    return ((unsigned)(unsigned short)f2h(a)) | (((unsigned)(unsigned short)f2h(b)) << 16);
}

// ---------------------------------------------------------------------------
// Repack: weights only -> MFMA B-fragment layout (f16). 550 blocks, tiny.
// ---------------------------------------------------------------------------
__global__ __launch_bounds__(256) void repack_kernel(
    const float* __restrict__ w_off, const float* __restrict__ w_dcn,
    short* __restrict__ ws)
{
    int idx = blockIdx.x * 256 + threadIdx.x;
    short* WB = ws;
    short* WD = ws + WB_ELEMS;
    if (idx < WB_ELEMS) {
        int j = idx & 7, l = (idx >> 3) & 63;
        int tn = idx >> 9;            // t*7 + n
        int n = tn % 7, t = tn / 7;
        int c = (l >> 4) * 8 + j;
        int oc = n * 16 + (l & 15);
        float v = (oc < OFFC) ? w_off[(t * CC + c) * OFFC + oc] : 0.f;
        WB[idx] = f2h(v);
    } else if (idx < WB_ELEMS + WD_ELEMS) {
        int idx2 = idx - WB_ELEMS;
        int j = idx2 & 7, l = (idx2 >> 3) & 63;
        int nt = idx2 >> 9;           // n*25 + t
        int t = nt % KT, n = nt / KT;
        int c = (l >> 4) * 8 + j;
        int f = n * 16 + (l & 15);
        WD[idx2] = f2h(w_dcn[(t * CC + c) * FF + f]);
    }
}

// PLANAR window layout: unit(q, c) = c*585 + q.
// Consecutive q (the per-phase lane axis in P2/P4) -> contiguous 16B units
// -> conflict-free ds_read_b128 phases. (Round-10's q*4+c^... was 4-way.)
__device__ __forceinline__ int wunit(int q, int c) {
    return c * WPIX + q;
}

// ---------------------------------------------------------------------------
// Fused kernel. Block = 32 px of one output row, 512 threads (8 waves).
//  P1: stage 13x45x32 f16 window from fp32 volume (planar LDS)
//  P2: offset GEMM (waves 0-6, n-tile each, 2 M-tiles) from window -> offtile
//  P3: 1600 (p,t,g) items -> packed pos {y0,x0,inw, h2(wy,wx)}
//  P4: wave=(mt,g,th): per tap build A-frag from window (contiguous ds reads;
//      global-fp32 fallback if out-of-window), 2 MFMAs (both f-tiles of g).
//  P5: tap-half reduce via LDS (aliases window), store.
// ---------------------------------------------------------------------------
__global__ __launch_bounds__(512, 4) void dcn_fused(
    const float* __restrict__ volume, const short* __restrict__ ws_ro,
    const float* __restrict__ b_off, const float* __restrict__ b_dcn,
    float* __restrict__ out)
{
    __shared__ __align__(16) char smem[56640];
    short*    window  = (short*)smem;              // 37,440 B
    uint2*    pos4    = (uint2*)(smem + 37440);    // 12,800 B: [25][2][32] uint2
    short*    offtile = (short*)(smem + 50240);    //  6,400 B: [32 px][100] f16
    f32x4*    red     = (f32x4*)smem;              //  8,192 B (aliases window, P5)

    const short* WB = ws_ro;
    const short* WD = ws_ro + WB_ELEMS;

    const int tid  = threadIdx.x;
    const int lane = tid & 63;
    const int wv   = tid >> 6;
    const int ox0  = blockIdx.x * NPX;
    const int oy   = blockIdx.y;
    const int b    = blockIdx.z;
    const float* Vb = volume + (size_t)b * (HH * WW * CC);

    // ---- P1: stage window (fp32 -> f16, clamped rows/cols). c fast in i for
    // coalesced global reads; planar LDS write is ~2-way (free tier).
    for (int i = tid; i < WUNITS; i += NTHREADS) {
        int c  = i & 3;
        int wc = (i >> 2) % WCOLS;
        int wr = (i >> 2) / WCOLS;
        int gy = oy - 2 + wr;  gy = max(0, min(HH - 1, gy));
        int gx = ox0 - 2 + wc; gx = max(0, min(WW - 1, gx));
        const float* src = Vb + ((size_t)gy * WW + gx) * CC + c * 8;
        float4 q0 = *(const float4*)src;
        float4 q1 = *(const float4*)(src + 4);
        uint4 r;
        r.x = pk2(q0.x, q0.y); r.y = pk2(q0.z, q0.w);
        r.z = pk2(q1.x, q1.y); r.w = pk2(q1.z, q1.w);
        int q = wr * WCOLS + wc;
        *(uint4*)&window[wunit(q, c) * 8] = r;
    }
    __syncthreads();

    // ---- P2: offset GEMM. wave w<7 -> n-tile w, both M-tiles, K=800.
    if (wv < 7) {
        const int pr = lane & 15, cq = lane >> 4;
        f32x4 a0 = (f32x4){0.f, 0.f, 0.f, 0.f};
        f32x4 a1 = (f32x4){0.f, 0.f, 0.f, 0.f};
        for (int fh = 0; fh < 5; ++fh) {
            #pragma unroll
            for (int fw = 0; fw < 5; ++fw) {
                int t = fh * 5 + fw;
                int q0 = (2 * fh + 2) * WCOLS + (pr + 2 * fw + 2);
                int q1 = q0 + 16;
                f16x8 af0 = *(const f16x8*)&window[wunit(q0, cq) * 8];
                f16x8 af1 = *(const f16x8*)&window[wunit(q1, cq) * 8];
                f16x8 bf = *(const f16x8*)&WB[(t * 7 + wv) * 512 + lane * 8];
                a0 = __builtin_amdgcn_mfma_f32_16x16x32_f16(af0, bf, a0, 0, 0, 0);
                a1 = __builtin_amdgcn_mfma_f32_16x16x32_f16(af1, bf, a1, 0, 0, 0);
            }
        }
        int col = lane & 15, q = lane >> 4;
        int oc = wv * 16 + col;
        if (oc < OFFC) {
            float bo = b_off[oc];
            #pragma unroll
            for (int r = 0; r < 4; ++r) {
                offtile[(q * 4 + r) * 100 + oc]      = f2h(a0[r] + bo);
                offtile[(16 + q * 4 + r) * 100 + oc] = f2h(a1[r] + bo);
            }
        }
    }
    __syncthreads();

    // ---- P3: positions -> packed {y0 | x0<<8 | inw<<16, h2(wy,wx)}
    for (int item = tid; item < 1600; item += NTHREADS) {
        int p = item & 31, g = (item >> 5) & 1, t = item >> 6;
        int pe = (ox0 + p < OW) ? p : (OW - 1 - ox0);
        int t5 = t / 5, tm5 = t - t5 * 5;
        float dy = h2f(offtile[pe * 100 + t * 4 + g]);
        float dx = h2f(offtile[pe * 100 + t * 4 + 2 + g]);
        float py = (float)(oy + 2 * t5) + dy;
        float px = (float)(ox0 + pe + 2 * tm5) + dx;
        py = fminf(fmaxf(py, 0.f), 127.f);
        px = fminf(fmaxf(px, 0.f), 127.f);
        float y0f = fminf(floorf(py), 126.f);
        float x0f = fminf(floorf(px), 126.f);
        float wy = py - y0f, wx = px - x0f;
        int y0 = (int)y0f, x0i = (int)x0f;
        int wr = y0 - oy + 2, wc = x0i - ox0 + 2;
        unsigned inw = ((unsigned)wr <= WROWS - 2u && (unsigned)wc <= WCOLS - 2u) ? 1u : 0u;
        pos4[(t * 2 + g) * 32 + p] =
            make_uint2((unsigned)y0 | ((unsigned)x0i << 8) | (inw << 16), pk2(wy, wx));
    }
    __syncthreads();

    // ---- P4: wave = (mt, g, th). Per tap: A-frag from window, 2 MFMAs.
    const int mt = wv & 1;
    const int g_ = (wv >> 1) & 1;
    const int th = wv >> 2;
    const int t0 = th ? 13 : 0, t1 = th ? 25 : 13;
    const int p_ = mt * 16 + (lane & 15);
    const int cq = lane >> 4;
    const short* wd0 = WD + ((g_ * 2 + 0) * KT) * 512 + lane * 8;
    const short* wd1 = WD + ((g_ * 2 + 1) * KT) * 512 + lane * 8;
    f32x4 acc0 = (f32x4){0.f, 0.f, 0.f, 0.f};
    f32x4 acc1 = (f32x4){0.f, 0.f, 0.f, 0.f};
    const h2 oneh = (h2){(_Float16)1.f, (_Float16)1.f};

    for (int t = t0; t < t1; ++t) {
        uint2 pw = pos4[(t * 2 + g_) * 32 + p_];
        unsigned pc = pw.x;
        int y0 = pc & 0x7f, x0i = (pc >> 8) & 0x7f;

        _Float16 wy = __builtin_bit_cast(h2, pw.y)[0];
        _Float16 wx = __builtin_bit_cast(h2, pw.y)[1];
        h2 vwy = (h2){wy, wy}, vwx = (h2){wx, wx};
        h2 iwy = oneh - vwy, iwx = oneh - vwx;
        h2 W00 = iwy * iwx, W01 = iwy * vwx, W10 = vwy * iwx, W11 = vwy * vwx;

        uint4 Au, Bu, Cu, Du;
        if (pc & 0x10000) {
            int q00 = (y0 - oy + 2) * WCOLS + (x0i - ox0 + 2);
            const short* wb = &window[(cq * WPIX + q00) * 8];
            Au = *(const uint4*)(wb);
            Bu = *(const uint4*)(wb + 8);               // q+1
            Cu = *(const uint4*)(wb + WCOLS * 8);       // q+45
            Du = *(const uint4*)(wb + (WCOLS + 1) * 8); // q+46
        } else {
            const float* vs = Vb + ((size_t)y0 * WW + x0i) * CC + cq * 8;
            #define LD8(dst, ptr) { float4 u0 = *(const float4*)(ptr); float4 u1 = *(const float4*)((ptr) + 4); \
                dst.x = pk2(u0.x, u0.y); dst.y = pk2(u0.z, u0.w); dst.z = pk2(u1.x, u1.y); dst.w = pk2(u1.z, u1.w); }
            LD8(Au, vs)
            LD8(Bu, vs + CC)
            LD8(Cu, vs + WW * CC)
            LD8(Du, vs + WW * CC + CC)
            #undef LD8
        }

        uint4 res;
        {
            h2 r0 = __builtin_bit_cast(h2, Au.x) * W00;
            r0 = __builtin_elementwise_fma(__builtin_bit_cast(h2, Bu.x), W01, r0);
            r0 = __builtin_elementwise_fma(__builtin_bit_cast(h2, Cu.x), W10, r0);
            r0 = __builtin_elementwise_fma(__builtin_bit_cast(h2, Du.x), W11, r0);
            res.x = __builtin_bit_cast(unsigned, r0);
            h2 r1 = __builtin_bit_cast(h2, Au.y) * W00;
            r1 = __builtin_elementwise_fma(__builtin_bit_cast(h2, Bu.y), W01, r1);
            r1 = __builtin_elementwise_fma(__builtin_bit_cast(h2, Cu.y), W10, r1);
            r1 = __builtin_elementwise_fma(__builtin_bit_cast(h2, Du.y), W11, r1);
            res.y = __builtin_bit_cast(unsigned, r1);
            h2 r2 = __builtin_bit_cast(h2, Au.z) * W00;
            r2 = __builtin_elementwise_fma(__builtin_bit_cast(h2, Bu.z), W01, r2);
            r2 = __builtin_elementwise_fma(__builtin_bit_cast(h2, Cu.z), W10, r2);
            r2 = __builtin_elementwise_fma(__builtin_bit_cast(h2, Du.z), W11, r2);
            res.z = __builtin_bit_cast(unsigned, r2);
            h2 r3 = __builtin_bit_cast(h2, Au.w) * W00;
            r3 = __builtin_elementwise_fma(__builtin_bit_cast(h2, Bu.w), W01, r3);
            r3 = __builtin_elementwise_fma(__builtin_bit_cast(h2, Cu.w), W10, r3);
            r3 = __builtin_elementwise_fma(__builtin_bit_cast(h2, Du.w), W11, r3);
            res.w = __builtin_bit_cast(unsigned, r3);
        }
        f16x8 af = __builtin_bit_cast(f16x8, res);
        acc0 = __builtin_amdgcn_mfma_f32_16x16x32_f16(af, *(const f16x8*)&wd0[t * 512], acc0, 0, 0, 0);
        acc1 = __builtin_amdgcn_mfma_f32_16x16x32_f16(af, *(const f16x8*)&wd1[t * 512], acc1, 0, 0, 0);
    }
    __syncthreads();   // all window/pos4 reads complete

    // ---- P5: tap-half reduce (red aliases window region) + store
    if (th) {
        int slot = (mt * 2 + g_) * 2;
        red[(slot + 0) * 64 + lane] = acc0;
        red[(slot + 1) * 64 + lane] = acc1;
    }
    __syncthreads();
    if (!th) {
        int slot = (mt * 2 + g_) * 2;
        acc0 += red[(slot + 0) * 64 + lane];
        acc1 += red[(slot + 1) * 64 + lane];
        int col = lane & 15, q = lane >> 4;
        int f0 = (g_ * 2 + 0) * 16 + col;
        int f1 = (g_ * 2 + 1) * 16 + col;
        float bd0 = b_dcn[f0], bd1 = b_dcn[f1];
        long pix0 = ((long)b * OH + oy) * OW + ox0;
        #pragma unroll
        for (int r = 0; r < 4; ++r) {
            int pp = mt * 16 + q * 4 + r;
            if (ox0 + pp < OW) {
                out[(pix0 + pp) * FF + f0] = acc0[r] + bd0;
                out[(pix0 + pp) * FF + f1] = acc1[r] + bd1;
            }
        }
    }
}

extern "C" void kernel_launch(void* const* d_in, const int* in_sizes, int n_in,
                              void* d_out, int out_size, void* d_ws, size_t ws_size,
                              hipStream_t stream) {
    const float* volume = (const float*)d_in[0];
    const float* w_off  = (const float*)d_in[1];
    const float* b_off  = (const float*)d_in[2];
    const float* w_dcn  = (const float*)d_in[3];
    const float* b_dcn  = (const float*)d_in[4];
    float* out = (float*)d_out;
    short* ws  = (short*)d_ws;   // 0.28 MB used (weights only)

    int repack_blocks = (WB_ELEMS + WD_ELEMS + 255) / 256;   // 550
    repack_kernel<<<repack_blocks, 256, 0, stream>>>(w_off, w_dcn, ws);

    dim3 g2((OW + NPX - 1) / NPX, OH, BB);   // 4 x 120 x 4 = 1920 blocks
    dcn_fused<<<g2, NTHREADS, 0, stream>>>(volume, ws, b_off, b_dcn, out);
}

// Round 12
// 123.462 us; speedup vs baseline: 1.1035x; 1.1035x over previous
//
#include <hip/hip_runtime.h>
#include <hip/hip_fp16.h>

#define BB 4
#define HH 128
#define WW 128
#define CC 32
#define OH 120
#define OW 120
#define KT 25
#define OFFC 100
#define FF 64
#define NPX 32
#define NTHREADS 512
#define QMAX 7   // max taps per quarter

typedef __attribute__((ext_vector_type(8))) short    s16x8;
typedef __attribute__((ext_vector_type(8))) _Float16 f16x8;
typedef __attribute__((ext_vector_type(2))) _Float16 h2;
typedef __attribute__((ext_vector_type(4))) float    f32x4;

// d_ws layout (short elements, fp16 bits):
//   WB:  [25 taps][7 n][64 lane][8]   89,600   (offset-conv weights, B-frag)
//   WD:  [4 n][25 taps][64 lane][8]   51,200   (dcn weights, B-frag)
//   V16: f16 volume [B][H][W][C]   2,097,152
#define WB_ELEMS   (KT * 7 * 64 * 8)
#define WD_ELEMS   (4 * KT * 64 * 8)
#define VOL_UNITS  (BB * HH * WW * CC / 8)      // 262,144 8-elem units
#define VOL16_OFF  (WB_ELEMS + WD_ELEMS)

__device__ __forceinline__ short f2h(float x) {
    _Float16 h = (_Float16)x;
    return __builtin_bit_cast(short, h);
}
__device__ __forceinline__ float h2f(short x) {
    return (float)__builtin_bit_cast(_Float16, x);
}

// ---------------------------------------------------------------------------
// Repack: weights -> MFMA B-fragment layout (f16); volume fp32 -> f16
// (volume branch: thread = one 8-elem unit, fully coalesced).
// ---------------------------------------------------------------------------
__global__ __launch_bounds__(256) void repack_kernel(
    const float* __restrict__ volume, const float* __restrict__ w_off,
    const float* __restrict__ w_dcn, short* __restrict__ ws)
{
    int idx = blockIdx.x * 256 + threadIdx.x;
    short* WB  = ws;
    short* WD  = ws + WB_ELEMS;
    short* V16 = ws + VOL16_OFF;
    if (idx < WB_ELEMS) {
        int j = idx & 7, l = (idx >> 3) & 63;
        int tn = idx >> 9;            // t*7 + n
        int n = tn % 7, t = tn / 7;
        int c = (l >> 4) * 8 + j;
        int oc = n * 16 + (l & 15);
        float v = (oc < OFFC) ? w_off[(t * CC + c) * OFFC + oc] : 0.f;
        WB[idx] = f2h(v);
    } else if (idx < WB_ELEMS + WD_ELEMS) {
        int idx2 = idx - WB_ELEMS;
        int j = idx2 & 7, l = (idx2 >> 3) & 63;
        int nt = idx2 >> 9;           // n*25 + t
        int t = nt % KT, n = nt / KT;
        int c = (l >> 4) * 8 + j;
        int f = n * 16 + (l & 15);
        WD[idx2] = f2h(w_dcn[(t * CC + c) * FF + f]);
    } else {
        int v = idx - (WB_ELEMS + WD_ELEMS);
        if (v < VOL_UNITS) {
            const float* src = volume + (size_t)v * 8;
            float4 q0 = *(const float4*)src;
            float4 q1 = *(const float4*)(src + 4);
            alignas(16) short tmp[8];
            tmp[0] = f2h(q0.x); tmp[1] = f2h(q0.y); tmp[2] = f2h(q0.z); tmp[3] = f2h(q0.w);
            tmp[4] = f2h(q1.x); tmp[5] = f2h(q1.y); tmp[6] = f2h(q1.z); tmp[7] = f2h(q1.w);
            *(s16x8*)&V16[(size_t)v * 8] = *(const s16x8*)tmp;
        }
    }
}

// ---------------------------------------------------------------------------
// Fused kernel: block = 32 px of one output row, 512 threads (8 waves).
//  P1: stage 9x40x32 f16 patch (swizzled, aliased over samp)
//  P2: offset GEMM (f16 MFMA, waves 0-6, 2 M-tiles) -> offtile (f16)
//  Four tap-quarters (7,6,6,6)  [round-12 change: was halves 13/12 — samp
//  28.7 KB instead of 53.2 KB -> block LDS 35.1 KB -> 4 blocks/CU]:
//   P4a: TLP gather: unit=(tap,g,px,cq): 4 lanes share a position, each lane
//        loads its 8 channels x 4 corners (uint4, f16 V16), pk-f16 combine,
//        one b128 store to xor-swizzled samp. All units independent.
//   P4b: wave=(mt,ftile): ntap x (ds_read_b128 af + global wd + MFMA).
// ---------------------------------------------------------------------------
__global__ __launch_bounds__(512, 4) void dcn_fused(
    const short* __restrict__ ws_ro, const float* __restrict__ b_off,
    const float* __restrict__ b_dcn, float* __restrict__ out)
{
    __shared__ __align__(16) char smem[35072];
    short* samp    = (short*)smem;             // 28,672 B: 7*32*8 units * 16B
    short* patch   = (short*)smem;             // 23,040 B (aliased, P1-P2 only)
    short* offtile = (short*)(smem + 28672);   //  6,400 B: [32 px][100] f16

    const short* WB  = ws_ro;
    const short* WD  = ws_ro + WB_ELEMS;
    const short* V16 = ws_ro + VOL16_OFF;

    const int tid  = threadIdx.x;
    const int lane = tid & 63;
    const int wv   = tid >> 6;
    const int ox0  = blockIdx.x * NPX;
    const int oy   = blockIdx.y;
    const int b    = blockIdx.z;
    const short* Vb = V16 + (size_t)b * (HH * WW * CC);

    // ---- P1: stage patch rows [oy,oy+9), cols [ox0,ox0+40) (col-clamped)
    for (int i = tid; i < 9 * 40 * 4; i += NTHREADS) {
        int cq = i & 3;
        int xi = (i >> 2) % 40;
        int yi = (i >> 2) / 40;
        int col = ox0 + xi; col = (col < WW) ? col : (WW - 1);
        s16x8 v = *(const s16x8*)&Vb[((size_t)(oy + yi) * WW + col) * CC + cq * 8];
        int u = ((yi * 40 + xi) << 2) + (cq ^ (xi & 3) ^ ((xi >> 2) & 3));
        *(s16x8*)&patch[u * 8] = v;
    }
    __syncthreads();

    // ---- P2: offset GEMM (f16). wave w<7 -> n-tile w, both M-tiles.
    if (wv < 7) {
        const int pr = lane & 15, cq = lane >> 4;
        f32x4 a0 = (f32x4){0.f, 0.f, 0.f, 0.f};
        f32x4 a1 = (f32x4){0.f, 0.f, 0.f, 0.f};
        for (int fh = 0; fh < 5; ++fh) {
            #pragma unroll
            for (int fw = 0; fw < 5; ++fw) {
                int t = fh * 5 + fw;
                int x0 = pr + 2 * fw, x1 = x0 + 16;
                f16x8 af0 = *(const f16x8*)&patch[((((2 * fh) * 40 + x0) << 2) + (cq ^ (x0 & 3) ^ ((x0 >> 2) & 3))) * 8];
                f16x8 af1 = *(const f16x8*)&patch[((((2 * fh) * 40 + x1) << 2) + (cq ^ (x1 & 3) ^ ((x1 >> 2) & 3))) * 8];
                f16x8 bf = *(const f16x8*)&WB[(t * 7 + wv) * 512 + lane * 8];
                a0 = __builtin_amdgcn_mfma_f32_16x16x32_f16(af0, bf, a0, 0, 0, 0);
                a1 = __builtin_amdgcn_mfma_f32_16x16x32_f16(af1, bf, a1, 0, 0, 0);
            }
        }
        int col = lane & 15, q = lane >> 4;
        int oc = wv * 16 + col;
        if (oc < OFFC) {
            float bo = b_off[oc];
            #pragma unroll
            for (int r = 0; r < 4; ++r) {
                offtile[(q * 4 + r) * 100 + oc]        = f2h(a0[r] + bo);
                offtile[(16 + q * 4 + r) * 100 + oc]   = f2h(a1[r] + bo);
            }
        }
    }
    __syncthreads();

    // ---- tap quarters
    const int mt = wv & 1;            // M-tile (16 px)
    const int ft = wv >> 1;           // f-tile 0..3
    const int g_ = ft >> 1;           // deform group of this f-tile
    const int p_ = mt * 16 + (lane & 15);
    const int cq_ = lane >> 4;
    f32x4 acc = (f32x4){0.f, 0.f, 0.f, 0.f};

    for (int h = 0; h < 4; ++h) {
        const int tbase = (h == 0) ? 0 : (h == 1) ? 7 : (h == 2) ? 13 : 19;
        const int ntap  = (h == 0) ? 7 : 6;

        // P4a: gather. unit u: c=u&3, p=(u>>2)&31, g=(u>>7)&1, tp=u>>8
        for (int u = tid; u < ntap * 256; u += NTHREADS) {
            int c  = u & 3;
            int p  = (u >> 2) & 31;
            int gg = (u >> 7) & 1;
            int tp = u >> 8;
            int t  = tbase + tp;
            int pe = (ox0 + p < OW) ? p : (OW - 1 - ox0);
            int t5 = t / 5, tm5 = t - t5 * 5;
            float dy = h2f(offtile[pe * 100 + t * 4 + gg]);
            float dx = h2f(offtile[pe * 100 + t * 4 + 2 + gg]);
            float py = (float)(oy + 2 * t5) + dy;
            float px = (float)(ox0 + pe + 2 * tm5) + dx;
            py = fminf(fmaxf(py, 0.f), 127.f);
            px = fminf(fmaxf(px, 0.f), 127.f);
            float y0f = fminf(floorf(py), 126.f);
            float x0f = fminf(floorf(px), 126.f);
            float wy = py - y0f, wx = px - x0f;
            int y0 = (int)y0f, x0i = (int)x0f;
            float w00 = (1.f - wy) * (1.f - wx);
            float w01 = (1.f - wy) * wx;
            float w10 = wy * (1.f - wx);
            float w11 = wy * wx;
            h2 W00 = (h2){(_Float16)w00, (_Float16)w00};
            h2 W01 = (h2){(_Float16)w01, (_Float16)w01};
            h2 W10 = (h2){(_Float16)w10, (_Float16)w10};
            h2 W11 = (h2){(_Float16)w11, (_Float16)w11};

            const short* vb0 = Vb + ((size_t)(y0 * WW + x0i)) * CC + c * 8;
            uint4 Au = *(const uint4*)(vb0);                 // v00, 8 ch
            uint4 Bu = *(const uint4*)(vb0 + CC);            // v01
            uint4 Cu = *(const uint4*)(vb0 + WW * CC);       // v10
            uint4 Du = *(const uint4*)(vb0 + WW * CC + CC);  // v11

            uint4 res;
            {
                h2 r0 = __builtin_bit_cast(h2, Au.x) * W00;
                r0 = __builtin_elementwise_fma(__builtin_bit_cast(h2, Bu.x), W01, r0);
                r0 = __builtin_elementwise_fma(__builtin_bit_cast(h2, Cu.x), W10, r0);
                r0 = __builtin_elementwise_fma(__builtin_bit_cast(h2, Du.x), W11, r0);
                res.x = __builtin_bit_cast(unsigned, r0);
                h2 r1 = __builtin_bit_cast(h2, Au.y) * W00;
                r1 = __builtin_elementwise_fma(__builtin_bit_cast(h2, Bu.y), W01, r1);
                r1 = __builtin_elementwise_fma(__builtin_bit_cast(h2, Cu.y), W10, r1);
                r1 = __builtin_elementwise_fma(__builtin_bit_cast(h2, Du.y), W11, r1);
                res.y = __builtin_bit_cast(unsigned, r1);
                h2 r2 = __builtin_bit_cast(h2, Au.z) * W00;
                r2 = __builtin_elementwise_fma(__builtin_bit_cast(h2, Bu.z), W01, r2);
                r2 = __builtin_elementwise_fma(__builtin_bit_cast(h2, Cu.z), W10, r2);
                r2 = __builtin_elementwise_fma(__builtin_bit_cast(h2, Du.z), W11, r2);
                res.z = __builtin_bit_cast(unsigned, r2);
                h2 r3 = __builtin_bit_cast(h2, Au.w) * W00;
                r3 = __builtin_elementwise_fma(__builtin_bit_cast(h2, Bu.w), W01, r3);
                r3 = __builtin_elementwise_fma(__builtin_bit_cast(h2, Cu.w), W10, r3);
                r3 = __builtin_elementwise_fma(__builtin_bit_cast(h2, Du.w), W11, r3);
                res.w = __builtin_bit_cast(unsigned, r3);
            }
            int unit = (tp * 32 + p) * 8 + ((gg * 4 + c) ^ (p & 7));
            *(uint4*)&samp[unit * 8] = res;
        }
        __syncthreads();

        // P4b: einsum for this quarter. wave (mt, ft), K = ntap taps x 32 ch.
        {
            const short* wd = WD + (ft * KT + tbase) * 512 + lane * 8;
            for (int tp = 0; tp < ntap; ++tp) {
                int unit = (tp * 32 + p_) * 8 + ((g_ * 4 + cq_) ^ (p_ & 7));
                f16x8 af = *(const f16x8*)&samp[unit * 8];
                f16x8 bf = *(const f16x8*)&wd[tp * 512];
                acc = __builtin_amdgcn_mfma_f32_16x16x32_f16(af, bf, acc, 0, 0, 0);
            }
        }
        __syncthreads();
    }

    // ---- epilogue: wave (mt, ft) owns 16px x 16f
    {
        int col = lane & 15, q = lane >> 4;
        int f = ft * 16 + col;
        float bd = b_dcn[f];
        long pix0 = ((long)b * OH + oy) * OW + ox0;
        #pragma unroll
        for (int r = 0; r < 4; ++r) {
            int pp = mt * 16 + q * 4 + r;
            if (ox0 + pp < OW)
                out[(pix0 + pp) * FF + f] = acc[r] + bd;
        }
    }
}

extern "C" void kernel_launch(void* const* d_in, const int* in_sizes, int n_in,
                              void* d_out, int out_size, void* d_ws, size_t ws_size,
                              hipStream_t stream) {
    const float* volume = (const float*)d_in[0];
    const float* w_off  = (const float*)d_in[1];
    const float* b_off  = (const float*)d_in[2];
    const float* w_dcn  = (const float*)d_in[3];
    const float* b_dcn  = (const float*)d_in[4];
    float* out = (float*)d_out;
    short* ws  = (short*)d_ws;   // 4.48 MB used

    int repack_threads = WB_ELEMS + WD_ELEMS + VOL_UNITS;   // 402,944
    int repack_blocks  = (repack_threads + 255) / 256;      // 1574
    repack_kernel<<<repack_blocks, 256, 0, stream>>>(volume, w_off, w_dcn, ws);

    dim3 g2((OW + NPX - 1) / NPX, OH, BB);   // 4 x 120 x 4 = 1920 blocks
    dcn_fused<<<g2, NTHREADS, 0, stream>>>(ws, b_off, b_dcn, out);
}